// Round 4
// baseline (216.458 us; speedup 1.0000x reference)
//
#include <hip/hip_runtime.h>

// RoI max pooling forward.
// x: (1, 512, 50, 50) f32; rois: (N,5) f32 [b, x1, y1, x2, y2]; out: (N,512,7,7) f32
//
// Bounds math must bit-match the XLA-compiled reference:
//  - XLA rewrites (roi / 7) -> roi * (1/7): reciprocal MULTIPLY in f32.
//    True division (f32 or f64, rounds 1/3) shifts bins at integer-boundary
//    ceil/floor cases -> O(1) absmax. Use x * (1.0f/7.0f).
//  - jnp.round == round-half-to-even -> rintf; *0.0625f is exact (pow2).
//  - hstart = clip(floor(bin_h*ph)+hs, 0, H); hend = clip(ceil(bin_h*(ph+1))+hs, 0, H)
//  - empty bin -> 0.0f

#define HH 50
#define WW 50
#define CC 512
#define OH 7
#define OW 7
#define NBINS (OH * OW)

__device__ __forceinline__ int4 compute_bounds(const float* __restrict__ r,
                                               int ph, int pw) {
    const float RCP7 = 1.0f / 7.0f;  // 0x3E124925, XLA's reciprocal for /7
    int ws = (int)rintf(r[1] * 0.0625f);
    int hs = (int)rintf(r[2] * 0.0625f);
    int we = (int)rintf(r[3] * 0.0625f);
    int he = (int)rintf(r[4] * 0.0625f);
    float roi_w = (float)max(we - ws + 1, 1);
    float roi_h = (float)max(he - hs + 1, 1);
    float bin_h = roi_h * RCP7;
    float bin_w = roi_w * RCP7;
    int hstart = min(max((int)floorf(bin_h * (float)ph) + hs, 0), HH);
    int hend   = min(max((int)ceilf (bin_h * (float)(ph + 1)) + hs, 0), HH);
    int wstart = min(max((int)floorf(bin_w * (float)pw) + ws, 0), WW);
    int wend   = min(max((int)ceilf (bin_w * (float)(pw + 1)) + ws, 0), WW);
    return make_int4(hstart, hend, wstart, wend);
}

// Kernel 1: one thread per (n, ph, pw) -> int4 bounds table in workspace.
__global__ __launch_bounds__(256) void roi_bounds(const float* __restrict__ rois,
                                                  int4* __restrict__ bounds,
                                                  int nbins_total) {
    int i = blockIdx.x * blockDim.x + threadIdx.x;
    if (i >= nbins_total) return;
    int pw = i % OW;
    int ph = (i / OW) % OH;
    int n  = i / NBINS;
    bounds[i] = compute_bounds(rois + (size_t)n * 5, ph, pw);
}

// Kernel 2: one thread per output element (n, c, ph, pw), pw fastest
// (coalesced writes). Reads bounds from the hot table.
__global__ __launch_bounds__(256) void roi_pool_fwd(const float* __restrict__ x,
                                                    const float* __restrict__ rois,
                                                    const int4* __restrict__ bounds,
                                                    float* __restrict__ out,
                                                    int total) {
    int idx = blockIdx.x * blockDim.x + threadIdx.x;
    if (idx >= total) return;

    int pw = idx % OW;
    int t  = idx / OW;
    int ph = t % OH;
    t /= OH;
    int c = t % CC;
    int n = t / CC;

    int4 bnd = bounds[n * NBINS + ph * OW + pw];
    int b = (int)rois[(size_t)n * 5];  // trunc, matches astype(int32)

    const float* plane = x + ((size_t)b * CC + c) * (HH * WW);
    float m = -INFINITY;
    for (int h = bnd.x; h < bnd.y; ++h) {
        const float* row = plane + h * WW;
        for (int w = bnd.z; w < bnd.w; ++w)
            m = fmaxf(m, row[w]);
    }
    bool nonempty = (bnd.x < bnd.y) && (bnd.z < bnd.w);
    out[idx] = nonempty ? m : 0.0f;
}

// Fallback (ws too small): bounds inline per output thread.
__global__ __launch_bounds__(256) void roi_pool_fused(const float* __restrict__ x,
                                                      const float* __restrict__ rois,
                                                      float* __restrict__ out,
                                                      int total) {
    int idx = blockIdx.x * blockDim.x + threadIdx.x;
    if (idx >= total) return;

    int pw = idx % OW;
    int t  = idx / OW;
    int ph = t % OH;
    t /= OH;
    int c = t % CC;
    int n = t / CC;

    const float* r = rois + (size_t)n * 5;
    int4 bnd = compute_bounds(r, ph, pw);
    int b = (int)r[0];

    const float* plane = x + ((size_t)b * CC + c) * (HH * WW);
    float m = -INFINITY;
    for (int h = bnd.x; h < bnd.y; ++h) {
        const float* row = plane + h * WW;
        for (int w = bnd.z; w < bnd.w; ++w)
            m = fmaxf(m, row[w]);
    }
    bool nonempty = (bnd.x < bnd.y) && (bnd.z < bnd.w);
    out[idx] = nonempty ? m : 0.0f;
}

extern "C" void kernel_launch(void* const* d_in, const int* in_sizes, int n_in,
                              void* d_out, int out_size, void* d_ws, size_t ws_size,
                              hipStream_t stream) {
    const float* x    = (const float*)d_in[0];
    const float* rois = (const float*)d_in[1];
    float* out = (float*)d_out;

    int nrois = in_sizes[1] / 5;
    int nbins_total = nrois * NBINS;
    int total = out_size;  // N * C * 7 * 7
    size_t need = (size_t)nbins_total * sizeof(int4);

    if (ws_size >= need) {
        int4* bounds = (int4*)d_ws;
        roi_bounds<<<(nbins_total + 255) / 256, 256, 0, stream>>>(rois, bounds,
                                                                  nbins_total);
        roi_pool_fwd<<<(total + 255) / 256, 256, 0, stream>>>(x, rois, bounds,
                                                              out, total);
    } else {
        roi_pool_fused<<<(total + 255) / 256, 256, 0, stream>>>(x, rois, out,
                                                                total);
    }
}

// Round 5
// 167.804 us; speedup vs baseline: 1.2899x; 1.2899x over previous
//
#include <hip/hip_runtime.h>

// RoI max pooling forward, divergence-free restructure.
// x: (1, 512, 50, 50) f32; rois: (N,5) f32; out: (N,512,7,7) f32
//
// R4 was VALU-bound (83% busy, ~330 insts/output): per-output idx decode +
// divergent trip counts (lanes spanned 49 bins) + scalar strided reads.
// R5: kernel A transposes x -> (HW, C) in d_ws. Kernel B: block = (n, cgroup
// of 64 ch), lane = channel, wave = bin -> uniform scalar loop bounds
// (readfirstlane), coalesced 256B loads, LDS-staged coalesced float4 writes.
//
// Bounds math bit-matches XLA: roi * (1.0f/7.0f) reciprocal multiply (NOT
// true division), rintf (round-half-even), *0.0625f exact, clip to [0,H].

#define HH 50
#define WW 50
#define CC 512
#define OH 7
#define OW 7
#define NBINS 49
#define HW (HH * WW)
#define CG 64

__device__ __forceinline__ int4 compute_bounds(const float* __restrict__ r,
                                               int ph, int pw) {
    const float RCP7 = 1.0f / 7.0f;  // XLA's reciprocal for /7
    int ws = (int)rintf(r[1] * 0.0625f);
    int hs = (int)rintf(r[2] * 0.0625f);
    int we = (int)rintf(r[3] * 0.0625f);
    int he = (int)rintf(r[4] * 0.0625f);
    float roi_w = (float)max(we - ws + 1, 1);
    float roi_h = (float)max(he - hs + 1, 1);
    float bin_h = roi_h * RCP7;
    float bin_w = roi_w * RCP7;
    int hstart = min(max((int)floorf(bin_h * (float)ph) + hs, 0), HH);
    int hend   = min(max((int)ceilf (bin_h * (float)(ph + 1)) + hs, 0), HH);
    int wstart = min(max((int)floorf(bin_w * (float)pw) + ws, 0), WW);
    int wend   = min(max((int)ceilf (bin_w * (float)(pw + 1)) + ws, 0), WW);
    return make_int4(hstart, hend, wstart, wend);
}

// Kernel A: x (C, HW) -> xt (HW, C), 64x64 LDS-tiled, both sides coalesced.
__global__ __launch_bounds__(256) void transpose_x(const float* __restrict__ x,
                                                   float* __restrict__ xt) {
    __shared__ float tile[64][65];
    int tx = threadIdx.x & 63;
    int tg = threadIdx.x >> 6;  // 0..3
    int hw0 = blockIdx.x * 64;
    int c0  = blockIdx.y * 64;
    #pragma unroll
    for (int i = 0; i < 16; ++i) {
        int r  = tg * 16 + i;        // c offset in tile
        int hw = hw0 + tx;
        if (hw < HW) tile[r][tx] = x[(size_t)(c0 + r) * HW + hw];
    }
    __syncthreads();
    #pragma unroll
    for (int i = 0; i < 16; ++i) {
        int r  = tg * 16 + i;        // hw offset in tile
        int hw = hw0 + r;
        if (hw < HW) xt[(size_t)hw * CC + c0 + tx] = tile[tx][r];
    }
}

// Kernel B: block = (n, cgroup); wave = bin; lane = channel.
__global__ __launch_bounds__(256) void roi_pool_t(const float* __restrict__ xt,
                                                  const float* __restrict__ rois,
                                                  float* __restrict__ out) {
    __shared__ int4  sbnd[NBINS];
    __shared__ float stile[CG * NBINS];  // [c_local][bin] — matches out layout
    int tid = threadIdx.x;
    int n   = blockIdx.x >> 3;           // CC/CG = 8 cgroups
    int cg  = blockIdx.x & 7;

    const float* r = rois + (size_t)n * 5;
    if (tid < NBINS) sbnd[tid] = compute_bounds(r, tid / OW, tid % OW);
    __syncthreads();

    int lane = tid & 63;
    int wv   = tid >> 6;
    const float* base = xt + cg * CG + lane;

    for (int bin = wv; bin < NBINS; bin += 4) {
        int4 bd = sbnd[bin];             // uniform (same addr all lanes)
        int h0 = __builtin_amdgcn_readfirstlane(bd.x);
        int h1 = __builtin_amdgcn_readfirstlane(bd.y);
        int w0 = __builtin_amdgcn_readfirstlane(bd.z);
        int w1 = __builtin_amdgcn_readfirstlane(bd.w);
        float m = -INFINITY;
        for (int h = h0; h < h1; ++h)
            for (int w = w0; w < w1; ++w)
                m = fmaxf(m, base[(size_t)(h * WW + w) * CC]);
        bool ne = (h0 < h1) && (w0 < w1);
        stile[lane * NBINS + bin] = ne ? m : 0.0f;  // stride 49: odd, conflict-free
    }
    __syncthreads();

    // 64*49 = 3136 contiguous floats = this block's exact out slice.
    size_t ob4 = (((size_t)n * CC + cg * CG) * NBINS) >> 2;
    float4* o4 = (float4*)out;
    const float4* s4 = (const float4*)stile;
    for (int t = tid; t < (CG * NBINS) / 4; t += 256)
        o4[ob4 + t] = s4[t];
}

// Fallback (ws too small for xt): R4's verified one-thread-per-output kernel.
__global__ __launch_bounds__(256) void roi_pool_fused(const float* __restrict__ x,
                                                      const float* __restrict__ rois,
                                                      float* __restrict__ out,
                                                      int total) {
    int idx = blockIdx.x * blockDim.x + threadIdx.x;
    if (idx >= total) return;
    int pw = idx % OW;
    int t  = idx / OW;
    int ph = t % OH;
    t /= OH;
    int c = t % CC;
    int n = t / CC;
    const float* r = rois + (size_t)n * 5;
    int4 bnd = compute_bounds(r, ph, pw);
    int b = (int)r[0];
    const float* plane = x + ((size_t)b * CC + c) * HW;
    float m = -INFINITY;
    for (int h = bnd.x; h < bnd.y; ++h) {
        const float* row = plane + h * WW;
        for (int w = bnd.z; w < bnd.w; ++w)
            m = fmaxf(m, row[w]);
    }
    bool nonempty = (bnd.x < bnd.y) && (bnd.z < bnd.w);
    out[idx] = nonempty ? m : 0.0f;
}

extern "C" void kernel_launch(void* const* d_in, const int* in_sizes, int n_in,
                              void* d_out, int out_size, void* d_ws, size_t ws_size,
                              hipStream_t stream) {
    const float* x    = (const float*)d_in[0];
    const float* rois = (const float*)d_in[1];
    float* out = (float*)d_out;
    int nrois = in_sizes[1] / 5;

    size_t need = (size_t)HW * CC * sizeof(float);  // 5.12 MB for xt
    if (ws_size >= need) {
        float* xt = (float*)d_ws;
        transpose_x<<<dim3((HW + 63) / 64, CC / 64), 256, 0, stream>>>(x, xt);
        roi_pool_t<<<nrois * (CC / CG), 256, 0, stream>>>(xt, rois, out);
    } else {
        roi_pool_fused<<<(out_size + 255) / 256, 256, 0, stream>>>(x, rois, out,
                                                                   out_size);
    }
}

// Round 7
// 154.249 us; speedup vs baseline: 1.4033x; 1.0879x over previous
//
#include <hip/hip_runtime.h>

// RoI max pooling forward, divergence-free + latency-batched.
// x: (1, 512, 50, 50) f32; rois: (N,5) f32; out: (N,512,7,7) f32
//
// R5 was dependent-load-latency-bound: runtime-trip inner loop emitted
// load->waitcnt->fmax per cell (1 outstanding L2 access/wave, ~200cy each).
// R6: process bins in 2x2 index-clamped blocks -> 4 independent loads per
// batch + fmax tree (duplicate cells harmless under max). Bounds stay
// wave-uniform scalars (readfirstlane) so addressing is SALU.
//
// Bounds math bit-matches XLA: roi * (1.0f/7.0f) reciprocal multiply (NOT
// true division), rintf (round-half-even), *0.0625f exact, clip to [0,H].

#define HH 50
#define WW 50
#define CC 512
#define OH 7
#define OW 7
#define NBINS 49
#define HW (HH * WW)
#define CG 64

__device__ __forceinline__ int4 compute_bounds(const float* __restrict__ r,
                                               int ph, int pw) {
    const float RCP7 = 1.0f / 7.0f;  // XLA's reciprocal for /7
    int ws = (int)rintf(r[1] * 0.0625f);
    int hs = (int)rintf(r[2] * 0.0625f);
    int we = (int)rintf(r[3] * 0.0625f);
    int he = (int)rintf(r[4] * 0.0625f);
    float roi_w = (float)max(we - ws + 1, 1);
    float roi_h = (float)max(he - hs + 1, 1);
    float bin_h = roi_h * RCP7;
    float bin_w = roi_w * RCP7;
    int hstart = min(max((int)floorf(bin_h * (float)ph) + hs, 0), HH);
    int hend   = min(max((int)ceilf (bin_h * (float)(ph + 1)) + hs, 0), HH);
    int wstart = min(max((int)floorf(bin_w * (float)pw) + ws, 0), WW);
    int wend   = min(max((int)ceilf (bin_w * (float)(pw + 1)) + ws, 0), WW);
    return make_int4(hstart, hend, wstart, wend);
}

// Kernel A: x (C, HW) -> xt (HW, C), 64x64 LDS-tiled, both sides coalesced.
__global__ __launch_bounds__(256) void transpose_x(const float* __restrict__ x,
                                                   float* __restrict__ xt) {
    __shared__ float tile[64][65];
    int tx = threadIdx.x & 63;
    int tg = threadIdx.x >> 6;  // 0..3
    int hw0 = blockIdx.x * 64;
    int c0  = blockIdx.y * 64;
    #pragma unroll
    for (int i = 0; i < 16; ++i) {
        int r  = tg * 16 + i;        // c offset in tile
        int hw = hw0 + tx;
        if (hw < HW) tile[r][tx] = x[(size_t)(c0 + r) * HW + hw];
    }
    __syncthreads();
    #pragma unroll
    for (int i = 0; i < 16; ++i) {
        int r  = tg * 16 + i;        // hw offset in tile
        int hw = hw0 + r;
        if (hw < HW) xt[(size_t)hw * CC + c0 + tx] = tile[tx][r];
    }
}

// Kernel B: block = (n, cgroup); wave = bin; lane = channel.
__global__ __launch_bounds__(256) void roi_pool_t(const float* __restrict__ xt,
                                                  const float* __restrict__ rois,
                                                  float* __restrict__ out) {
    __shared__ int4  sbnd[NBINS];
    __shared__ float stile[CG * NBINS];  // [c_local][bin] — matches out layout
    int tid = threadIdx.x;
    int n   = blockIdx.x >> 3;           // CC/CG = 8 cgroups
    int cg  = blockIdx.x & 7;

    const float* r = rois + (size_t)n * 5;
    if (tid < NBINS) sbnd[tid] = compute_bounds(r, tid / OW, tid % OW);
    __syncthreads();

    int lane = tid & 63;
    int wv   = tid >> 6;
    const float* base = xt + cg * CG + lane;

    for (int bin = wv; bin < NBINS; bin += 4) {
        int4 bd = sbnd[bin];             // uniform (same addr all lanes)
        int h0 = __builtin_amdgcn_readfirstlane(bd.x);
        int h1 = __builtin_amdgcn_readfirstlane(bd.y);
        int w0 = __builtin_amdgcn_readfirstlane(bd.z);
        int w1 = __builtin_amdgcn_readfirstlane(bd.w);
        float m = -INFINITY;
        // 2x2 index-clamped batches: 4 independent loads -> 1 waitcnt ->
        // fmax tree. Duplicated (clamped) cells are harmless under max.
        for (int h = h0; h < h1; h += 2) {
            int hb = min(h + 1, h1 - 1);
            int ra = h  * (WW * CC);
            int rb = hb * (WW * CC);
            for (int w = w0; w < w1; w += 2) {
                int wb = min(w + 1, w1 - 1);
                int ca = w  * CC;
                int cb = wb * CC;
                float v00 = base[ra + ca];
                float v01 = base[ra + cb];
                float v10 = base[rb + ca];
                float v11 = base[rb + cb];
                m = fmaxf(m, fmaxf(fmaxf(v00, v01), fmaxf(v10, v11)));
            }
        }
        bool ne = (h0 < h1) && (w0 < w1);
        stile[lane * NBINS + bin] = ne ? m : 0.0f;  // stride 49: conflict-free
    }
    __syncthreads();

    // 64*49 = 3136 contiguous floats = this block's exact out slice.
    size_t ob4 = (((size_t)n * CC + cg * CG) * NBINS) >> 2;
    float4* o4 = (float4*)out;
    const float4* s4 = (const float4*)stile;
    for (int t = tid; t < (CG * NBINS) / 4; t += 256)
        o4[ob4 + t] = s4[t];
}

// Fallback (ws too small for xt): R4's verified one-thread-per-output kernel.
__global__ __launch_bounds__(256) void roi_pool_fused(const float* __restrict__ x,
                                                      const float* __restrict__ rois,
                                                      float* __restrict__ out,
                                                      int total) {
    int idx = blockIdx.x * blockDim.x + threadIdx.x;
    if (idx >= total) return;
    int pw = idx % OW;
    int t  = idx / OW;
    int ph = t % OH;
    t /= OH;
    int c = t % CC;
    int n = t / CC;
    const float* r = rois + (size_t)n * 5;
    int4 bnd = compute_bounds(r, ph, pw);
    int b = (int)r[0];
    const float* plane = x + ((size_t)b * CC + c) * HW;
    float m = -INFINITY;
    for (int h = bnd.x; h < bnd.y; ++h) {
        const float* row = plane + h * WW;
        for (int w = bnd.z; w < bnd.w; ++w)
            m = fmaxf(m, row[w]);
    }
    bool nonempty = (bnd.x < bnd.y) && (bnd.z < bnd.w);
    out[idx] = nonempty ? m : 0.0f;
}

extern "C" void kernel_launch(void* const* d_in, const int* in_sizes, int n_in,
                              void* d_out, int out_size, void* d_ws, size_t ws_size,
                              hipStream_t stream) {
    const float* x    = (const float*)d_in[0];
    const float* rois = (const float*)d_in[1];
    float* out = (float*)d_out;
    int nrois = in_sizes[1] / 5;

    size_t need = (size_t)HW * CC * sizeof(float);  // 5.12 MB for xt
    if (ws_size >= need) {
        float* xt = (float*)d_ws;
        transpose_x<<<dim3((HW + 63) / 64, CC / 64), 256, 0, stream>>>(x, xt);
        roi_pool_t<<<nrois * (CC / CG), 256, 0, stream>>>(xt, rois, out);
    } else {
        roi_pool_fused<<<(out_size + 255) / 256, 256, 0, stream>>>(x, rois, out,
                                                                   out_size);
    }
}

// Round 8
// 145.773 us; speedup vs baseline: 1.4849x; 1.0581x over previous
//
#include <hip/hip_runtime.h>

// RoI max pooling forward: divergence-free, latency-batched, float2-widened.
// x: (1, 512, 50, 50) f32; rois: (N,5) f32; out: (N,512,7,7) f32
//
// R7 post-mortem: 2x2 batching cut latency chains but kernel became
// issue-bound (~55% VALUBusy) - per-bin overhead (bounds read, addressing,
// clamp-duplicated loads) dominated. R8: lane covers TWO channels via
// dwordx2 (CG=128) -> half the blocks/loads/overhead; scalar fast path for
// the dominant 1x1 bins skips the 2x2 clamp duplicates.
//
// Bounds math bit-matches XLA: roi * (1.0f/7.0f) reciprocal multiply (NOT
// true division), rintf (round-half-even), *0.0625f exact, clip to [0,H].

#define HH 50
#define WW 50
#define CC 512
#define OH 7
#define OW 7
#define NBINS 49
#define HW (HH * WW)
#define CG 128

__device__ __forceinline__ int4 compute_bounds(const float* __restrict__ r,
                                               int ph, int pw) {
    const float RCP7 = 1.0f / 7.0f;  // XLA's reciprocal for /7
    int ws = (int)rintf(r[1] * 0.0625f);
    int hs = (int)rintf(r[2] * 0.0625f);
    int we = (int)rintf(r[3] * 0.0625f);
    int he = (int)rintf(r[4] * 0.0625f);
    float roi_w = (float)max(we - ws + 1, 1);
    float roi_h = (float)max(he - hs + 1, 1);
    float bin_h = roi_h * RCP7;
    float bin_w = roi_w * RCP7;
    int hstart = min(max((int)floorf(bin_h * (float)ph) + hs, 0), HH);
    int hend   = min(max((int)ceilf (bin_h * (float)(ph + 1)) + hs, 0), HH);
    int wstart = min(max((int)floorf(bin_w * (float)pw) + ws, 0), WW);
    int wend   = min(max((int)ceilf (bin_w * (float)(pw + 1)) + ws, 0), WW);
    return make_int4(hstart, hend, wstart, wend);
}

// Kernel A: x (C, HW) -> xt (HW, C), 64x64 LDS-tiled, both sides coalesced.
__global__ __launch_bounds__(256) void transpose_x(const float* __restrict__ x,
                                                   float* __restrict__ xt) {
    __shared__ float tile[64][65];
    int tx = threadIdx.x & 63;
    int tg = threadIdx.x >> 6;  // 0..3
    int hw0 = blockIdx.x * 64;
    int c0  = blockIdx.y * 64;
    #pragma unroll
    for (int i = 0; i < 16; ++i) {
        int r  = tg * 16 + i;        // c offset in tile
        int hw = hw0 + tx;
        if (hw < HW) tile[r][tx] = x[(size_t)(c0 + r) * HW + hw];
    }
    __syncthreads();
    #pragma unroll
    for (int i = 0; i < 16; ++i) {
        int r  = tg * 16 + i;        // hw offset in tile
        int hw = hw0 + r;
        if (hw < HW) xt[(size_t)hw * CC + c0 + tx] = tile[tx][r];
    }
}

// Kernel B: block = (n, cgroup of 128 ch); wave = bin; lane = channel PAIR.
__global__ __launch_bounds__(256) void roi_pool_t(const float* __restrict__ xt,
                                                  const float* __restrict__ rois,
                                                  float* __restrict__ out) {
    __shared__ int4  sbnd[NBINS];
    __shared__ float stile[CG * NBINS];  // [c_local][bin] — matches out layout
    int tid = threadIdx.x;
    int n   = blockIdx.x >> 2;           // CC/CG = 4 cgroups
    int cg  = blockIdx.x & 3;

    const float* r = rois + (size_t)n * 5;
    if (tid < NBINS) sbnd[tid] = compute_bounds(r, tid / OW, tid % OW);
    __syncthreads();

    int lane = tid & 63;
    int wv   = tid >> 6;
    const float* base = xt + cg * CG + lane * 2;  // 8B-aligned: float2 loads

    for (int bin = wv; bin < NBINS; bin += 4) {
        int4 bd = sbnd[bin];             // uniform (same addr all lanes)
        int h0 = __builtin_amdgcn_readfirstlane(bd.x);
        int h1 = __builtin_amdgcn_readfirstlane(bd.y);
        int w0 = __builtin_amdgcn_readfirstlane(bd.z);
        int w1 = __builtin_amdgcn_readfirstlane(bd.w);
        float m0 = -INFINITY, m1 = -INFINITY;
        if (((h1 - h0) | (w1 - w0)) == 1) {
            // dominant case: 1x1 bin — single load (scalar-uniform branch)
            float2 v = *(const float2*)&base[(h0 * WW + w0) * CC];
            m0 = v.x; m1 = v.y;
        } else {
            // 2x2 index-clamped batches: 4 independent loads -> 1 waitcnt ->
            // fmax tree. Duplicated (clamped) cells are harmless under max.
            for (int h = h0; h < h1; h += 2) {
                int hb = min(h + 1, h1 - 1);
                int ra = h  * (WW * CC);
                int rb = hb * (WW * CC);
                for (int w = w0; w < w1; w += 2) {
                    int wb = min(w + 1, w1 - 1);
                    float2 v00 = *(const float2*)&base[ra + w  * CC];
                    float2 v01 = *(const float2*)&base[ra + wb * CC];
                    float2 v10 = *(const float2*)&base[rb + w  * CC];
                    float2 v11 = *(const float2*)&base[rb + wb * CC];
                    m0 = fmaxf(m0, fmaxf(fmaxf(v00.x, v01.x), fmaxf(v10.x, v11.x)));
                    m1 = fmaxf(m1, fmaxf(fmaxf(v00.y, v01.y), fmaxf(v10.y, v11.y)));
                }
            }
        }
        bool ne = (h0 < h1) && (w0 < w1);
        // stride-49-word writes: banks 2*lane mod 32 -> 2 lanes/bank (free)
        stile[(lane * 2 + 0) * NBINS + bin] = ne ? m0 : 0.0f;
        stile[(lane * 2 + 1) * NBINS + bin] = ne ? m1 : 0.0f;
    }
    __syncthreads();

    // 128*49 = 6272 contiguous floats = this block's exact out slice.
    size_t ob4 = (((size_t)n * CC + cg * CG) * NBINS) >> 2;
    float4* o4 = (float4*)out;
    const float4* s4 = (const float4*)stile;
    for (int t = tid; t < (CG * NBINS) / 4; t += 256)
        o4[ob4 + t] = s4[t];
}

// Fallback (ws too small for xt): R4's verified one-thread-per-output kernel.
__global__ __launch_bounds__(256) void roi_pool_fused(const float* __restrict__ x,
                                                      const float* __restrict__ rois,
                                                      float* __restrict__ out,
                                                      int total) {
    int idx = blockIdx.x * blockDim.x + threadIdx.x;
    if (idx >= total) return;
    int pw = idx % OW;
    int t  = idx / OW;
    int ph = t % OH;
    t /= OH;
    int c = t % CC;
    int n = t / CC;
    const float* r = rois + (size_t)n * 5;
    int4 bnd = compute_bounds(r, ph, pw);
    int b = (int)r[0];
    const float* plane = x + ((size_t)b * CC + c) * HW;
    float m = -INFINITY;
    for (int h = bnd.x; h < bnd.y; ++h) {
        const float* row = plane + h * WW;
        for (int w = bnd.z; w < bnd.w; ++w)
            m = fmaxf(m, row[w]);
    }
    bool nonempty = (bnd.x < bnd.y) && (bnd.z < bnd.w);
    out[idx] = nonempty ? m : 0.0f;
}

extern "C" void kernel_launch(void* const* d_in, const int* in_sizes, int n_in,
                              void* d_out, int out_size, void* d_ws, size_t ws_size,
                              hipStream_t stream) {
    const float* x    = (const float*)d_in[0];
    const float* rois = (const float*)d_in[1];
    float* out = (float*)d_out;
    int nrois = in_sizes[1] / 5;

    size_t need = (size_t)HW * CC * sizeof(float);  // 5.12 MB for xt
    if (ws_size >= need) {
        float* xt = (float*)d_ws;
        transpose_x<<<dim3((HW + 63) / 64, CC / 64), 256, 0, stream>>>(x, xt);
        roi_pool_t<<<nrois * (CC / CG), 256, 0, stream>>>(xt, rois, out);
    } else {
        roi_pool_fused<<<(out_size + 255) / 256, 256, 0, stream>>>(x, rois, out,
                                                                   out_size);
    }
}